// Round 1
// baseline (1141.988 us; speedup 1.0000x reference)
//
#include <hip/hip_runtime.h>
#include <math.h>

#define L_SEQ 512
#define NB 8
#define DM 256
#define DI 512
#define NSTATE 32
#define DTR 16

static __device__ __forceinline__ float siluf(float x){
  return x / (1.f + __expf(-x));
}

// ---------------- LayerNorm: one wave per row (256 cols) ----------------
__global__ __launch_bounds__(256) void ln_kernel(const float* __restrict__ x,
    const float* __restrict__ g, const float* __restrict__ b, float* __restrict__ out)
{
  int row = blockIdx.x*4 + (threadIdx.x>>6);
  int lane = threadIdx.x & 63;
  const float* xr = x + (size_t)row*DM;
  float v0 = xr[lane], v1 = xr[lane+64], v2 = xr[lane+128], v3 = xr[lane+192];
  float s = v0+v1+v2+v3;
  #pragma unroll
  for (int m=1;m<64;m<<=1) s += __shfl_xor(s, m);
  float mu = s*(1.f/DM);
  float d0=v0-mu,d1=v1-mu,d2=v2-mu,d3=v3-mu;
  float vs = d0*d0+d1*d1+d2*d2+d3*d3;
  #pragma unroll
  for (int m=1;m<64;m<<=1) vs += __shfl_xor(vs, m);
  float rstd = rsqrtf(vs*(1.f/DM)+1e-5f);
  float* orow = out + (size_t)row*DM;
  orow[lane]     = d0*rstd*g[lane]     + b[lane];
  orow[lane+64]  = d1*rstd*g[lane+64]  + b[lane+64];
  orow[lane+128] = d2*rstd*g[lane+128] + b[lane+128];
  orow[lane+192] = d3*rstd*g[lane+192] + b[lane+192];
}

// ---------------- fp32 tiled GEMM: C[M,N] (op)= A[M,K] @ B[N,K]^T ----------------
// EPI: 0 store, 1 accumulate, 2 softplus(x+bias), 3 x+bias
// M must be a multiple of 128 (always 4096 here); K a multiple of 16; N guarded.
template<int EPI>
__global__ __launch_bounds__(256) void gemm_nt(
    const float* __restrict__ A, int lda,
    const float* __restrict__ Bw, int ldb,
    float* __restrict__ C, int ldc,
    int N, int K, const float* __restrict__ bias)
{
  const int BM=128, BN=64, BK=16;
  __shared__ float As[BK][BM];
  __shared__ float Bs[BK][BN];
  int tid = threadIdx.x;
  int bn0 = blockIdx.x*BN;
  int bm0 = blockIdx.y*BM;
  int tx = tid & 15, ty = tid >> 4;
  float acc[8][4];
  #pragma unroll
  for (int i=0;i<8;i++)
    #pragma unroll
    for (int j=0;j<4;j++) acc[i][j]=0.f;

  for (int k0=0; k0<K; k0+=BK){
    #pragma unroll
    for (int it=0; it<2; ++it){            // A tile: 128x16 = 512 float4
      int f4 = tid + 256*it;
      int r = f4 >> 2, c4 = (f4 & 3)*4;
      float4 av = *(const float4*)&A[(size_t)(bm0+r)*lda + k0 + c4];
      As[c4+0][r]=av.x; As[c4+1][r]=av.y; As[c4+2][r]=av.z; As[c4+3][r]=av.w;
    }
    {                                      // B tile: 64x16 = 256 float4
      int r = tid >> 2, c4 = (tid & 3)*4;
      float4 bv = make_float4(0.f,0.f,0.f,0.f);
      if (bn0 + r < N) bv = *(const float4*)&Bw[(size_t)(bn0+r)*ldb + k0 + c4];
      Bs[c4+0][r]=bv.x; Bs[c4+1][r]=bv.y; Bs[c4+2][r]=bv.z; Bs[c4+3][r]=bv.w;
    }
    __syncthreads();
    #pragma unroll
    for (int k=0;k<BK;k++){
      float4 a0 = *(const float4*)&As[k][ty*8];
      float4 a1 = *(const float4*)&As[k][ty*8+4];
      float4 bv = *(const float4*)&Bs[k][tx*4];
      float ar[8] = {a0.x,a0.y,a0.z,a0.w,a1.x,a1.y,a1.z,a1.w};
      float br[4] = {bv.x,bv.y,bv.z,bv.w};
      #pragma unroll
      for (int i=0;i<8;i++)
        #pragma unroll
        for (int j=0;j<4;j++)
          acc[i][j] = fmaf(ar[i], br[j], acc[i][j]);
    }
    __syncthreads();
  }
  #pragma unroll
  for (int i=0;i<8;i++){
    int r = bm0 + ty*8 + i;
    #pragma unroll
    for (int j=0;j<4;j++){
      int c = bn0 + tx*4 + j;
      if (c < N){
        size_t off = (size_t)r*ldc + c;
        float v = acc[i][j];
        if (EPI==1)      C[off] += v;
        else if (EPI==2){ float xv=v+bias[c];
                          C[off] = fmaxf(xv,0.f) + log1pf(__expf(-fabsf(xv))); }
        else if (EPI==3) C[off] = v + bias[c];
        else             C[off] = v;
      }
    }
  }
}

// ---------------- depthwise causal conv (fwd) + anticausal (rev), + bias + SiLU ----
// Input: xz [B*L, 1024], channels 0..511. Outputs in ORIGINAL time order.
template<int KC>
__global__ __launch_bounds__(256) void conv_kernel(
  const float* __restrict__ xz, const float* __restrict__ w, const float* __restrict__ cb,
  float* __restrict__ xiF, float* __restrict__ xiR)
{
  int idx = blockIdx.x*256 + threadIdx.x;   // B*L*DI = 2^21 threads
  int c = idx & (DI-1);
  int t = (idx >> 9) & (L_SEQ-1);
  int bb = idx >> 18;
  const float* base = xz + ((size_t)bb*L_SEQ)*1024 + c;
  float wr[KC];
  #pragma unroll
  for (int j=0;j<KC;j++) wr[j] = w[c*KC+j];
  float bias = cb[c];
  float accF = bias, accR = bias;
  #pragma unroll
  for (int j=0;j<KC;j++){
    int tf = t - (KC-1) + j;               // causal: w[K-1] hits current step
    if (tf >= 0)     accF += wr[j]*base[(size_t)tf*1024];
    int tr = t + (KC-1) - j;               // reversed-seq conv in original order
    if (tr < L_SEQ)  accR += wr[j]*base[(size_t)tr*1024];
  }
  xiF[idx] = siluf(accF);
  xiR[idx] = siluf(accR);
}

// ---------------- selective scan, both directions in one launch ----------------
// Half-wave (32 lanes) per (b,d) channel; lane = state index n. h in a register.
// grid: 1024 blocks = dir(2) x b(8) x dblk(64); block = 256 thr = 8 channels.
// Epilogue fused: y = (scan_y + xi*Dp) * silu(z), written in original order.
__global__ __launch_bounds__(256) void scan_kernel(
  const float* __restrict__ xdF, const float* __restrict__ xdR,   // [B*L,80]
  const float* __restrict__ dtF, const float* __restrict__ dtR,   // [B*L,512]
  const float* __restrict__ xiF, const float* __restrict__ xiR,   // [B*L,512]
  const float* __restrict__ xz,                                    // z = cols 512..1023
  const float* __restrict__ Alog, const float* __restrict__ Dp,
  float* __restrict__ yF, float* __restrict__ yR)
{
  int bi = blockIdx.x;
  int dir  = bi >> 9;
  int b    = (bi >> 6) & 7;
  int d0   = (bi & 63) * 8;
  const float* xd  = dir ? xdR : xdF;
  const float* dtp = dir ? dtR : dtF;
  const float* xip = dir ? xiR : xiF;
  float*       yo  = dir ? yR  : yF;

  int tid = threadIdx.x;
  int wave = tid >> 6, lane = tid & 63;
  int ch = wave*2 + (lane>>5);       // 0..7 (block-local channel)
  int n  = lane & 31;                // state index
  int d  = d0 + ch;

  float Areg = -__expf(Alog[d*NSTATE + n]);
  float Al   = Areg * 1.44269504089f;       // exp(dt*A) = exp2(dt*A*log2e)
  float Dpv  = Dp[d];
  float h = 0.f;

  __shared__ float2 BC[64][32];       // per-t B,C (shared by all channels)
  __shared__ float4 DXZ[64][8];       // per-(t,ch) dt, xi, z
  __shared__ float  YO[64][8];

  for (int chunk=0; chunk<8; ++chunk){
    int s0 = chunk*64;
    for (int idx=tid; idx<64*32; idx+=256){
      int li = idx>>5, nn = idx&31;
      int st = s0+li; int t = dir ? (L_SEQ-1-st) : st;
      size_t row = ((size_t)b*L_SEQ + t)*80;
      BC[li][nn] = make_float2(xd[row + DTR + nn], xd[row + DTR + NSTATE + nn]);
    }
    for (int idx=tid; idx<64*8; idx+=256){
      int li = idx>>3, cc = idx&7;
      int st = s0+li; int t = dir ? (L_SEQ-1-st) : st;
      size_t row = (size_t)b*L_SEQ + t;
      DXZ[li][cc] = make_float4(dtp[row*DI + d0+cc],
                                xip[row*DI + d0+cc],
                                xz[row*1024 + DI + d0+cc], 0.f);
    }
    __syncthreads();
    for (int li=0; li<64; ++li){
      float4 q = DXZ[li][ch];
      float dt = q.x, xi = q.y, z = q.z;
      float2 bc = BC[li][n];
      float dA = __builtin_amdgcn_exp2f(dt * Al);
      h = dA*h + dt*xi*bc.x;
      float yp = h * bc.y;
      #pragma unroll
      for (int m=1;m<32;m<<=1) yp += __shfl_xor(yp, m);
      if (n==0){
        YO[li][ch] = (yp + xi*Dpv) * siluf(z);
      }
    }
    __syncthreads();
    for (int idx=tid; idx<64*8; idx+=256){
      int li = idx>>3, cc = idx&7;
      int st = s0+li; int t = dir ? (L_SEQ-1-st) : st;
      yo[((size_t)b*L_SEQ + t)*DI + d0+cc] = YO[li][cc];
    }
    __syncthreads();
  }
}

// ---------------- gate + fuse ----------------
__global__ __launch_bounds__(256) void fuse_kernel(const float* __restrict__ gpre,
   const float* __restrict__ gb, const float* __restrict__ ff, const float* __restrict__ fr,
   float* __restrict__ fused)
{
  int idx = blockIdx.x*256 + threadIdx.x;
  int nidx = idx & (DM-1);
  float g = 1.f/(1.f+__expf(-(gpre[idx]+gb[nidx])));
  fused[idx] = g*ff[idx] + (1.f-g)*fr[idx];
}

extern "C" void kernel_launch(void* const* d_in, const int* in_sizes, int n_in,
                              void* d_out, int out_size, void* d_ws, size_t ws_size,
                              hipStream_t stream)
{
  (void)in_sizes; (void)n_in; (void)out_size; (void)ws_size;
  const float* x    = (const float*)d_in[0];
  const float* ln_g = (const float*)d_in[1];
  const float* ln_b = (const float*)d_in[2];
  const float* Win[2]  = {(const float*)d_in[3],  (const float*)d_in[12]};
  const float* convw[2]= {(const float*)d_in[4],  (const float*)d_in[13]};
  const float* convb[2]= {(const float*)d_in[5],  (const float*)d_in[14]};
  const float* Wx[2]   = {(const float*)d_in[6],  (const float*)d_in[15]};
  const float* Wdt[2]  = {(const float*)d_in[7],  (const float*)d_in[16]};
  const float* dtb[2]  = {(const float*)d_in[8],  (const float*)d_in[17]};
  const float* Alog[2] = {(const float*)d_in[9],  (const float*)d_in[18]};
  const float* Dpp[2]  = {(const float*)d_in[10], (const float*)d_in[19]};
  const float* Wout[2] = {(const float*)d_in[11], (const float*)d_in[20]};
  const float* gate_W = (const float*)d_in[21];
  const float* gate_b = (const float*)d_in[22];
  const float* op_W   = (const float*)d_in[23];
  const float* op_b   = (const float*)d_in[24];
  float* out = (float*)d_out;

  float* ws = (float*)d_ws;
  size_t off = 0;
  auto alloc = [&](size_t nelem){ float* p = ws + off; off += nelem; return p; };
  const size_t R = (size_t)NB * L_SEQ;      // 4096 rows
  float* xn  = alloc(R*DM);
  float* xzb = alloc(R*1024);
  float* xiF = alloc(R*DI);
  float* xiR = alloc(R*DI);
  float* xdF = alloc(R*80);
  float* xdR = alloc(R*80);
  float* dtF = alloc(R*DI);
  float* dtR = alloc(R*DI);
  float* yF  = alloc(R*DI);
  float* yR  = alloc(R*DI);
  float* ff  = alloc(R*DM);
  float* fr  = alloc(R*DM);
  float* gpre= alloc(R*DM);
  float* fus = alloc(R*DM);

  ln_kernel<<<R/4, 256, 0, stream>>>(x, ln_g, ln_b, xn);

  for (int m=0; m<2; ++m){
    // xz = xn @ Win^T   [4096,256]x[1024,256]^T
    gemm_nt<0><<<dim3(1024/64, 4096/128), 256, 0, stream>>>(xn, DM, Win[m], DM, xzb, 1024, 1024, DM, nullptr);
    if (m==0) conv_kernel<4><<<8192,256,0,stream>>>(xzb, convw[m], convb[m], xiF, xiR);
    else      conv_kernel<8><<<8192,256,0,stream>>>(xzb, convw[m], convb[m], xiF, xiR);
    // x_dbl = xi @ Wx^T  [4096,512]x[80,512]^T
    gemm_nt<0><<<dim3(2, 32), 256, 0, stream>>>(xiF, DI, Wx[m], DI, xdF, 80, 80, DI, nullptr);
    gemm_nt<0><<<dim3(2, 32), 256, 0, stream>>>(xiR, DI, Wx[m], DI, xdR, 80, 80, DI, nullptr);
    // dt = softplus(x_dbl[:,:16] @ Wdt^T + dtb)   [4096,16]x[512,16]^T
    gemm_nt<2><<<dim3(8, 32), 256, 0, stream>>>(xdF, 80, Wdt[m], DTR, dtF, DI, DI, DTR, dtb[m]);
    gemm_nt<2><<<dim3(8, 32), 256, 0, stream>>>(xdR, 80, Wdt[m], DTR, dtR, DI, DI, DTR, dtb[m]);
    // selective scan (both dirs), fused epilogue y=(ys+xi*Dp)*silu(z)
    scan_kernel<<<1024, 256, 0, stream>>>(xdF,xdR,dtF,dtR,xiF,xiR,xzb,Alog[m],Dpp[m],yF,yR);
    // f_dir (+)= y @ Wout^T   [4096,512]x[256,512]^T
    if (m==0){
      gemm_nt<0><<<dim3(4,32),256,0,stream>>>(yF, DI, Wout[m], DI, ff, DM, DM, DI, nullptr);
      gemm_nt<0><<<dim3(4,32),256,0,stream>>>(yR, DI, Wout[m], DI, fr, DM, DM, DI, nullptr);
    } else {
      gemm_nt<1><<<dim3(4,32),256,0,stream>>>(yF, DI, Wout[m], DI, ff, DM, DM, DI, nullptr);
      gemm_nt<1><<<dim3(4,32),256,0,stream>>>(yR, DI, Wout[m], DI, fr, DM, DM, DI, nullptr);
    }
  }
  // gate pre-activation: ff @ gW[:,:256]^T + fr @ gW[:,256:]^T
  gemm_nt<0><<<dim3(4,32),256,0,stream>>>(ff, DM, gate_W,    2*DM, gpre, DM, DM, DM, nullptr);
  gemm_nt<1><<<dim3(4,32),256,0,stream>>>(fr, DM, gate_W+DM, 2*DM, gpre, DM, DM, DM, nullptr);
  fuse_kernel<<<R*DM/256, 256, 0, stream>>>(gpre, gate_b, ff, fr, fus);
  // out = fused @ op_W^T + op_b
  gemm_nt<3><<<dim3(4,32),256,0,stream>>>(fus, DM, op_W, DM, out, DM, DM, DM, op_b);
}

// Round 2
// 623.227 us; speedup vs baseline: 1.8324x; 1.8324x over previous
//
#include <hip/hip_runtime.h>
#include <math.h>

#define L_SEQ 512
#define NB 8
#define DM 256
#define DI 512
#define NSTATE 32
#define DTR 16
#define R_ROWS 4096   // NB*L_SEQ

static __device__ __forceinline__ float siluf(float x){
  return x / (1.f + __expf(-x));
}

// ---------------- LayerNorm: one wave per row (256 cols) ----------------
__global__ __launch_bounds__(256) void ln_kernel(const float* __restrict__ x,
    const float* __restrict__ g, const float* __restrict__ b, float* __restrict__ out)
{
  int row = blockIdx.x*4 + (threadIdx.x>>6);
  int lane = threadIdx.x & 63;
  const float* xr = x + (size_t)row*DM;
  float v0 = xr[lane], v1 = xr[lane+64], v2 = xr[lane+128], v3 = xr[lane+192];
  float s = v0+v1+v2+v3;
  #pragma unroll
  for (int m=1;m<64;m<<=1) s += __shfl_xor(s, m);
  float mu = s*(1.f/DM);
  float d0=v0-mu,d1=v1-mu,d2=v2-mu,d3=v3-mu;
  float vs = d0*d0+d1*d1+d2*d2+d3*d3;
  #pragma unroll
  for (int m=1;m<64;m<<=1) vs += __shfl_xor(vs, m);
  float rstd = rsqrtf(vs*(1.f/DM)+1e-5f);
  float* orow = out + (size_t)row*DM;
  orow[lane]     = d0*rstd*g[lane]     + b[lane];
  orow[lane+64]  = d1*rstd*g[lane+64]  + b[lane+64];
  orow[lane+128] = d2*rstd*g[lane+128] + b[lane+128];
  orow[lane+192] = d3*rstd*g[lane+192] + b[lane+192];
}

// ---------------- 128x128 fp32 GEMM body: C[M,N] = A[M,K] @ B[N,K]^T ----------------
// EPI: 0 store, 3 x+bias.  Requires M%128==0, N%128==0, K%16==0.
template<int EPI>
__device__ __forceinline__ void gemm128_body(
    float (&As)[16][132], float (&Bs)[16][132],
    const float* __restrict__ A, int lda,
    const float* __restrict__ Bw, int ldb,
    float* __restrict__ C, int ldc, int K,
    const float* __restrict__ bias, int bm0, int bn0)
{
  int tid = threadIdx.x;
  int tx = tid & 15, ty = tid >> 4;
  float acc[8][8];
  #pragma unroll
  for (int i=0;i<8;i++)
    #pragma unroll
    for (int j=0;j<8;j++) acc[i][j]=0.f;

  for (int k0=0; k0<K; k0+=16){
    #pragma unroll
    for (int it=0; it<2; ++it){
      int f4 = tid + it*256;
      int r = f4 >> 2, c4 = (f4 & 3)*4;
      float4 av = *(const float4*)&A[(size_t)(bm0+r)*lda + k0 + c4];
      As[c4+0][r]=av.x; As[c4+1][r]=av.y; As[c4+2][r]=av.z; As[c4+3][r]=av.w;
      float4 bv = *(const float4*)&Bw[(size_t)(bn0+r)*ldb + k0 + c4];
      Bs[c4+0][r]=bv.x; Bs[c4+1][r]=bv.y; Bs[c4+2][r]=bv.z; Bs[c4+3][r]=bv.w;
    }
    __syncthreads();
    #pragma unroll
    for (int k=0;k<16;k++){
      float a[8], b[8];
      *(float4*)&a[0] = *(const float4*)&As[k][ty*8];
      *(float4*)&a[4] = *(const float4*)&As[k][ty*8+4];
      *(float4*)&b[0] = *(const float4*)&Bs[k][tx*8];
      *(float4*)&b[4] = *(const float4*)&Bs[k][tx*8+4];
      #pragma unroll
      for (int i=0;i<8;i++)
        #pragma unroll
        for (int j=0;j<8;j++)
          acc[i][j] = fmaf(a[i], b[j], acc[i][j]);
    }
    __syncthreads();
  }
  #pragma unroll
  for (int i=0;i<8;i++){
    int r = bm0 + ty*8 + i;
    #pragma unroll
    for (int j=0;j<8;j++){
      int c = bn0 + tx*8 + j;
      size_t off = (size_t)r*ldc + c;
      float v = acc[i][j];
      if (EPI==3) C[off] = v + bias[c];
      else        C[off] = v;
    }
  }
}

template<int EPI>
__global__ __launch_bounds__(256) void gemm128(
    const float* __restrict__ A, int lda,
    const float* __restrict__ Bw, int ldb,
    float* __restrict__ C, int ldc, int K, const float* __restrict__ bias)
{
  __shared__ float As[16][132];
  __shared__ float Bs[16][132];
  gemm128_body<EPI>(As, Bs, A, lda, Bw, ldb, C, ldc, K, bias,
                    blockIdx.y*128, blockIdx.x*128);
}

// Batched Wout: z = (m<<1)|dir. y layout [m][dir][R][DI]. Writes ffr_m[4096][512]
// column-block per dir (cols dir*256 .. dir*256+255).
__global__ __launch_bounds__(256) void wout_batch(
    const float* __restrict__ y, const float* __restrict__ W0,
    const float* __restrict__ W1, float* __restrict__ ffrA, float* __restrict__ ffrB)
{
  __shared__ float As[16][132];
  __shared__ float Bs[16][132];
  int z = blockIdx.z;
  int m = z >> 1, dir = z & 1;
  const float* A  = y + ((size_t)m*2 + dir)*R_ROWS*DI;
  const float* Bw = m ? W1 : W0;
  float* C = (m ? ffrB : ffrA) + dir*DM;
  gemm128_body<0>(As, Bs, A, DI, Bw, DI, C, 2*DM, DI, nullptr,
                  blockIdx.y*128, blockIdx.x*128);
}

// ---------------- 128x64 fp32 GEMM (N guarded): C = (A[+A2]) @ B^T ----------------
// EPI: 0 store, 3 x+bias
template<int EPI, bool DUALA>
__global__ __launch_bounds__(256) void gemm_nt64(
    const float* __restrict__ A, const float* __restrict__ A2, int lda,
    const float* __restrict__ Bw, int ldb,
    float* __restrict__ C, int ldc,
    int N, int K, const float* __restrict__ bias)
{
  const int BM=128, BN=64, BK=16;
  __shared__ float As[BK][BM+4];
  __shared__ float Bs[BK][BN+4];
  int tid = threadIdx.x;
  int bn0 = blockIdx.x*BN;
  int bm0 = blockIdx.y*BM;
  int tx = tid & 15, ty = tid >> 4;
  float acc[8][4];
  #pragma unroll
  for (int i=0;i<8;i++)
    #pragma unroll
    for (int j=0;j<4;j++) acc[i][j]=0.f;

  for (int k0=0; k0<K; k0+=BK){
    #pragma unroll
    for (int it=0; it<2; ++it){
      int f4 = tid + 256*it;
      int r = f4 >> 2, c4 = (f4 & 3)*4;
      float4 av = *(const float4*)&A[(size_t)(bm0+r)*lda + k0 + c4];
      if (DUALA){
        float4 a2 = *(const float4*)&A2[(size_t)(bm0+r)*lda + k0 + c4];
        av.x+=a2.x; av.y+=a2.y; av.z+=a2.z; av.w+=a2.w;
      }
      As[c4+0][r]=av.x; As[c4+1][r]=av.y; As[c4+2][r]=av.z; As[c4+3][r]=av.w;
    }
    {
      int r = tid >> 2, c4 = (tid & 3)*4;
      float4 bv = make_float4(0.f,0.f,0.f,0.f);
      if (bn0 + r < N) bv = *(const float4*)&Bw[(size_t)(bn0+r)*ldb + k0 + c4];
      Bs[c4+0][r]=bv.x; Bs[c4+1][r]=bv.y; Bs[c4+2][r]=bv.z; Bs[c4+3][r]=bv.w;
    }
    __syncthreads();
    #pragma unroll
    for (int k=0;k<BK;k++){
      float ar[8], br[4];
      *(float4*)&ar[0] = *(const float4*)&As[k][ty*8];
      *(float4*)&ar[4] = *(const float4*)&As[k][ty*8+4];
      *(float4*)&br[0] = *(const float4*)&Bs[k][tx*4];
      #pragma unroll
      for (int i=0;i<8;i++)
        #pragma unroll
        for (int j=0;j<4;j++)
          acc[i][j] = fmaf(ar[i], br[j], acc[i][j]);
    }
    __syncthreads();
  }
  #pragma unroll
  for (int i=0;i<8;i++){
    int r = bm0 + ty*8 + i;
    #pragma unroll
    for (int j=0;j<4;j++){
      int c = bn0 + tx*4 + j;
      if (c < N){
        size_t off = (size_t)r*ldc + c;
        float v = acc[i][j];
        if (EPI==3) C[off] = v + bias[c];
        else        C[off] = v;
      }
    }
  }
}

// ---------------- depthwise causal conv (fwd) + anticausal (rev), + bias + SiLU ----
template<int KC>
__global__ __launch_bounds__(256) void conv_kernel(
  const float* __restrict__ xz, const float* __restrict__ w, const float* __restrict__ cb,
  float* __restrict__ xiF, float* __restrict__ xiR)
{
  int idx = blockIdx.x*256 + threadIdx.x;   // B*L*DI threads
  int c = idx & (DI-1);
  int t = (idx >> 9) & (L_SEQ-1);
  int bb = idx >> 18;
  const float* base = xz + ((size_t)bb*L_SEQ)*1024 + c;
  float wr[KC];
  #pragma unroll
  for (int j=0;j<KC;j++) wr[j] = w[c*KC+j];
  float bias = cb[c];
  float accF = bias, accR = bias;
  #pragma unroll
  for (int j=0;j<KC;j++){
    int tf = t - (KC-1) + j;
    if (tf >= 0)     accF += wr[j]*base[(size_t)tf*1024];
    int tr = t + (KC-1) - j;
    if (tr < L_SEQ)  accR += wr[j]*base[(size_t)tr*1024];
  }
  xiF[idx] = siluf(accF);
  xiR[idx] = siluf(accR);
}

// ---------------- selective scan, both dirs, dt-GEMM fused ----------------
// Block = 256 threads = 8 channels x 32 states, for one (dir,b,d-block of 8).
// Two-pass y-reduction via LDS (no serial shuffle chain). Grid 1024 = 4/CU.
__global__ __launch_bounds__(256) void scan_kernel(
  const float* __restrict__ xd,    // [2R,80]  (F rows then R rows; R in orig order)
  const float* __restrict__ xi,    // [2R,512]
  const float* __restrict__ xz,    // [R,1024] (z = cols 512..1023)
  const float* __restrict__ WdtW,  // [512,16]
  const float* __restrict__ dtb,   // [512]
  const float* __restrict__ Alog,  // [512,32]
  const float* __restrict__ Dp,    // [512]
  float* __restrict__ y)           // [2,R,512]
{
  int bi = blockIdx.x;
  int dir = bi >> 9, b = (bi >> 6) & 7, d0 = (bi & 63) * 8;
  const float* xdp = xd + (size_t)dir*R_ROWS*80;
  const float* xip = xi + (size_t)dir*R_ROWS*DI;
  float* yo = y + (size_t)dir*R_ROWS*DI;
  size_t bL = (size_t)b*L_SEQ;

  __shared__ float  XD[32][84];       // staged x_dbl rows (dt_in|B|C), pad->84
  __shared__ float  HC[8][16][36];    // h*C per (ch, t-sub, n), pad->36
  __shared__ float2 DTs[32][8];       // (dt, dt*xi) per (t, ch)
  __shared__ float2 XZs[32][8];       // (xi, z) per (t, ch)
  __shared__ float  YO[32][8];
  __shared__ float  WT[16][8];        // Wdt^T slice for these 8 channels
  __shared__ float  DTB[8], DPS[8];

  int tid = threadIdx.x;
  if (tid < 128){ int k = tid>>3, cc = tid&7; WT[k][cc] = WdtW[(d0+cc)*DTR + k]; }
  else if (tid < 136) DTB[tid-128] = dtb[d0 + tid-128];
  else if (tid < 144) DPS[tid-136] = Dp[d0 + tid-136];

  int wv = tid>>6, l64 = tid&63;
  int ch = wv*2 + (l64>>5);           // scan-phase channel 0..7
  int n  = l64 & 31;                  // state index
  float Al = -__expf(Alog[(d0+ch)*NSTATE + n]) * 1.44269504089f;
  float h = 0.f;

  int li8 = tid>>3, c8 = tid&7;       // 32x8 thread map (stage/B/E phases)
  int chD = tid>>5, t2 = tid&31;      // reduce-phase map

  for (int chunk=0; chunk<16; ++chunk){
    int s0 = chunk*32;
    // E: write out previous chunk's YO (coalesced-ish), overlapped with staging
    if (chunk){
      int st = s0 - 32 + li8;
      int t = dir ? (L_SEQ-1-st) : st;
      yo[(bL + t)*DI + d0 + c8] = YO[li8][c8];
    }
    // A: stage XD (32 rows x 80) and (xi,z)
    {
      int rr = tid>>3, ee = tid&7;
      int st = s0 + rr; int t = dir ? (L_SEQ-1-st) : st;
      const float* src = xdp + (bL + t)*80;
      #pragma unroll
      for (int j=0;j<10;j++) XD[rr][ee + j*8] = src[ee + j*8];
      XZs[li8][c8] = make_float2(xip[(bL + t)*DI + d0 + c8],
                                 xz[(bL + t)*1024 + DI + d0 + c8]);
    }
    __syncthreads();
    // B: dt = softplus(xd[:,0:16] @ WdtT + dtb), fused
    {
      float s = DTB[c8];
      #pragma unroll
      for (int k=0;k<DTR;k++) s = fmaf(XD[li8][k], WT[k][c8], s);
      float dtv = fmaxf(s,0.f) + log1pf(__expf(-fabsf(s)));
      DTs[li8][c8] = make_float2(dtv, dtv * XZs[li8][c8].x);
    }
    __syncthreads();
    #pragma unroll
    for (int half=0; half<2; ++half){
      // C: 16 scan steps, write h*C to LDS (no cross-lane ops)
      #pragma unroll
      for (int li=0; li<16; ++li){
        int li2 = half*16 + li;
        float2 dd = DTs[li2][ch];
        float Bv = XD[li2][DTR + n];
        float Cv = XD[li2][DTR + NSTATE + n];
        float dA = __builtin_amdgcn_exp2f(dd.x * Al);
        h = fmaf(dA, h, dd.y * Bv);
        HC[ch][li][n] = h * Cv;
      }
      __syncthreads();
      // D: reduce 32 states per t; 2 threads per (ch,t)
      {
        int t = t2 >> 1, nh = t2 & 1;
        const float* hp = &HC[chD][t][nh*16];
        float4 s1 = *(const float4*)&hp[0];
        float4 s2 = *(const float4*)&hp[4];
        float4 s3 = *(const float4*)&hp[8];
        float4 s4 = *(const float4*)&hp[12];
        float ssum = ((s1.x+s1.y)+(s1.z+s1.w)) + ((s2.x+s2.y)+(s2.z+s2.w))
                   + ((s3.x+s3.y)+(s3.z+s3.w)) + ((s4.x+s4.y)+(s4.z+s4.w));
        ssum += __shfl_xor(ssum, 1);
        if (!nh){
          int li2 = half*16 + t;
          float2 xzv = XZs[li2][chD];
          YO[li2][chD] = (ssum + xzv.x * DPS[chD]) * siluf(xzv.y);
        }
      }
      __syncthreads();
    }
  }
  // final writeout (chunk 15)
  {
    int st = 480 + li8;
    int t = dir ? (L_SEQ-1-st) : st;
    yo[(bL + t)*DI + d0 + c8] = YO[li8][c8];
  }
}

// ---------------- gate + fuse ----------------
__global__ __launch_bounds__(256) void fuse_kernel(const float* __restrict__ gpre,
   const float* __restrict__ gb, const float* __restrict__ ffrA,
   const float* __restrict__ ffrB, float* __restrict__ fused)
{
  int idx = blockIdx.x*256 + threadIdx.x;
  int r = idx >> 8, c = idx & (DM-1);
  size_t ro = (size_t)r*2*DM;
  float ffv = ffrA[ro + c]      + ffrB[ro + c];
  float frv = ffrA[ro + DM + c] + ffrB[ro + DM + c];
  float g = 1.f/(1.f+__expf(-(gpre[idx] + gb[c])));
  fused[idx] = g*ffv + (1.f-g)*frv;
}

extern "C" void kernel_launch(void* const* d_in, const int* in_sizes, int n_in,
                              void* d_out, int out_size, void* d_ws, size_t ws_size,
                              hipStream_t stream)
{
  (void)in_sizes; (void)n_in; (void)out_size; (void)ws_size;
  const float* x    = (const float*)d_in[0];
  const float* ln_g = (const float*)d_in[1];
  const float* ln_b = (const float*)d_in[2];
  const float* Win[2]  = {(const float*)d_in[3],  (const float*)d_in[12]};
  const float* convw[2]= {(const float*)d_in[4],  (const float*)d_in[13]};
  const float* convb[2]= {(const float*)d_in[5],  (const float*)d_in[14]};
  const float* Wx[2]   = {(const float*)d_in[6],  (const float*)d_in[15]};
  const float* Wdt[2]  = {(const float*)d_in[7],  (const float*)d_in[16]};
  const float* dtb[2]  = {(const float*)d_in[8],  (const float*)d_in[17]};
  const float* Alog[2] = {(const float*)d_in[9],  (const float*)d_in[18]};
  const float* Dpp[2]  = {(const float*)d_in[10], (const float*)d_in[19]};
  const float* Wout[2] = {(const float*)d_in[11], (const float*)d_in[20]};
  const float* gate_W = (const float*)d_in[21];
  const float* gate_b = (const float*)d_in[22];
  const float* op_W   = (const float*)d_in[23];
  const float* op_b   = (const float*)d_in[24];
  float* out = (float*)d_out;

  float* ws = (float*)d_ws;
  size_t off = 0;
  auto alloc = [&](size_t nelem){ float* p = ws + off; off += nelem; return p; };
  const size_t R = R_ROWS;
  float* xn   = alloc(R*DM);
  float* xzb  = alloc(R*1024);
  float* xi   = alloc(2*R*DI);     // [dir][R][DI]
  float* xdd  = alloc(2*R*80);     // [dir][R][80]
  float* y    = alloc(4*R*DI);     // [m][dir][R][DI]
  float* ffrA = alloc(R*2*DM);     // m=0: [R][ff|fr]
  float* ffrB = alloc(R*2*DM);     // m=1
  float* gpre = alloc(R*DM);
  float* fus  = alloc(R*DM);

  ln_kernel<<<R/4, 256, 0, stream>>>(x, ln_g, ln_b, xn);

  for (int m=0; m<2; ++m){
    // xz = xn @ Win^T   [4096,256] x [1024,256]^T
    gemm128<0><<<dim3(8, 32), 256, 0, stream>>>(xn, DM, Win[m], DM, xzb, 1024, DM, nullptr);
    if (m==0) conv_kernel<4><<<8192,256,0,stream>>>(xzb, convw[m], convb[m], xi, xi + R*DI);
    else      conv_kernel<8><<<8192,256,0,stream>>>(xzb, convw[m], convb[m], xi, xi + R*DI);
    // x_dbl = xi @ Wx^T  [8192,512] x [80,512]^T   (both dirs at once)
    gemm_nt64<0,false><<<dim3(2, 64), 256, 0, stream>>>(xi, nullptr, DI, Wx[m], DI, xdd, 80, 80, DI, nullptr);
    // scan (dt fused), both dirs
    scan_kernel<<<1024, 256, 0, stream>>>(xdd, xi, xzb, Wdt[m], dtb[m], Alog[m], Dpp[m],
                                          y + (size_t)m*2*R*DI);
  }
  // f = y @ Wout^T for all 4 (m,dir), into ffrA/ffrB col-blocks
  wout_batch<<<dim3(2, 32, 4), 256, 0, stream>>>(y, Wout[0], Wout[1], ffrA, ffrB);
  // gate pre-activation: (ffrA+ffrB) @ gate_W^T  [4096,512] x [256,512]^T
  gemm_nt64<0,true><<<dim3(4, 32), 256, 0, stream>>>(ffrA, ffrB, 2*DM, gate_W, 2*DM, gpre, DM, DM, 2*DM, nullptr);
  fuse_kernel<<<R*DM/256, 256, 0, stream>>>(gpre, gate_b, ffrA, ffrB, fus);
  // out = fused @ op_W^T + op_b
  gemm_nt64<3,false><<<dim3(4, 32), 256, 0, stream>>>(fus, nullptr, DM, op_W, DM, out, DM, DM, DM, op_b);
}

// Round 3
// 465.872 us; speedup vs baseline: 2.4513x; 1.3378x over previous
//
#include <hip/hip_runtime.h>
#include <math.h>

#define L_SEQ 512
#define NB 8
#define DM 256
#define DI 512
#define NSTATE 32
#define DTR 16
#define R_ROWS 4096   // NB*L_SEQ

typedef unsigned short ushort_t;
typedef __bf16 bf16t;
typedef bf16t bf16x8 __attribute__((ext_vector_type(8)));
typedef float f32x4 __attribute__((ext_vector_type(4)));

static __device__ __forceinline__ float siluf(float x){
  return x / (1.f + __expf(-x));
}
static __device__ __forceinline__ ushort_t f2bf(float f){
  unsigned u = __float_as_uint(f);
  u += 0x7fff + ((u>>16)&1);
  return (ushort_t)(u>>16);
}
static __device__ __forceinline__ float bf2f(ushort_t h){
  return __uint_as_float(((unsigned)h)<<16);
}

// ---------------- weight prep: fp32 -> bf16 hi/lo planes ----------------
__global__ __launch_bounds__(256) void prep_weights(
  const float* __restrict__ Wi0, const float* __restrict__ Wi1,
  const float* __restrict__ Wx0, const float* __restrict__ Wx1,
  const float* __restrict__ Wo0, const float* __restrict__ Wo1,
  const float* __restrict__ gW,  const float* __restrict__ oW,
  ushort_t* WiH0, ushort_t* WiL0, ushort_t* WiH1, ushort_t* WiL1,
  ushort_t* WxH0, ushort_t* WxL0, ushort_t* WxH1, ushort_t* WxL1,
  ushort_t* WoH,  ushort_t* WoL,  ushort_t* gH, ushort_t* gL,
  ushort_t* oH, ushort_t* oL)
{
  int i = blockIdx.x*256 + threadIdx.x;
  float v; ushort_t *ph, *pl; int oi;
  if (i < 262144){ v = Wi0[i]; ph=WiH0; pl=WiL0; oi=i; }
  else if (i < 524288){ oi=i-262144; v = Wi1[oi]; ph=WiH1; pl=WiL1; }
  else if (i < 565248){ oi=i-524288; v = Wx0[oi]; ph=WxH0; pl=WxL0; }
  else if (i < 606208){ oi=i-565248; v = Wx1[oi]; ph=WxH1; pl=WxL1; }
  else if (i < 868352){ oi=i-606208; int n=oi>>10, k=oi&1023;
                        v = (k<512)? Wo0[n*512+k] : Wo1[n*512+k-512];
                        ph=WoH; pl=WoL; }
  else if (i < 999424){ oi=i-868352; v = gW[oi]; ph=gH; pl=gL; }
  else { oi=i-999424; v = oW[oi]; ph=oH; pl=oL; }
  ushort_t h = f2bf(v);
  ph[oi] = h;
  pl[oi] = f2bf(v - bf2f(h));
}

// ---------------- LayerNorm -> bf16 hi/lo planes ----------------
__global__ __launch_bounds__(256) void ln_kernel(const float* __restrict__ x,
    const float* __restrict__ g, const float* __restrict__ b,
    ushort_t* __restrict__ xnh, ushort_t* __restrict__ xnl)
{
  int row = blockIdx.x*4 + (threadIdx.x>>6);
  int lane = threadIdx.x & 63;
  const float* xr = x + (size_t)row*DM;
  float v0 = xr[lane], v1 = xr[lane+64], v2 = xr[lane+128], v3 = xr[lane+192];
  float s = v0+v1+v2+v3;
  #pragma unroll
  for (int m=1;m<64;m<<=1) s += __shfl_xor(s, m);
  float mu = s*(1.f/DM);
  float d0=v0-mu,d1=v1-mu,d2=v2-mu,d3=v3-mu;
  float vs = d0*d0+d1*d1+d2*d2+d3*d3;
  #pragma unroll
  for (int m=1;m<64;m<<=1) vs += __shfl_xor(vs, m);
  float rstd = rsqrtf(vs*(1.f/DM)+1e-5f);
  size_t ro = (size_t)row*DM;
  #pragma unroll
  for (int j=0;j<4;j++){
    int c = lane + j*64;
    float val = (j==0?d0:j==1?d1:j==2?d2:d3)*rstd*g[c] + b[c];
    ushort_t h = f2bf(val);
    xnh[ro+c] = h;
    xnl[ro+c] = f2bf(val - bf2f(h));
  }
}

// ---------------- split-bf16 MFMA GEMM: C[M,N] = A[M,K] @ B[N,K]^T ----------------
// A,B given as bf16 hi/lo planes (row-major, ld=K). BN=128 fixed.
// EPI: 0 = store fp32 C; 1 = store fp32 C + bias; 2 = store fp32 C AND bf16 planes.
template<int BM, int EPI>
__global__ __launch_bounds__(256) void gemm_mfma(
    const ushort_t* __restrict__ Ahi, const ushort_t* __restrict__ Alo, long Az,
    const ushort_t* __restrict__ Bhi, const ushort_t* __restrict__ Blo,
    int K, int N,
    float* __restrict__ C, int ldc, int Czoff,
    ushort_t* __restrict__ Phi, ushort_t* __restrict__ Plo, int ldp,
    const float* __restrict__ bias)
{
  constexpr int MT = (BM==128)?4:2;
  __shared__ ushort_t Al[BM][64];
  __shared__ ushort_t Bl[128][64];
  int tid = threadIdx.x;
  int z = blockIdx.z;
  const ushort_t* Ah = Ahi + (long)z*Az;
  const ushort_t* Alw = Alo + (long)z*Az;
  float* Cz = C + (long)z*Czoff;
  int bm0 = blockIdx.y*BM, bn0 = blockIdx.x*128;

  int w = tid>>6, l = tid&63;
  int wm = w>>1, wn = w&1;
  int lr = l&15, q = l>>4;

  f32x4 acc[MT][4];
  #pragma unroll
  for (int i=0;i<MT;i++)
    #pragma unroll
    for (int j=0;j<4;j++) acc[i][j] = (f32x4){0.f,0.f,0.f,0.f};

  for (int k0=0; k0<K; k0+=32){
    // stage A: BM rows x 8 chunks of 16B (chunk = kq*2+plane), XOR-swizzled
    #pragma unroll
    for (int p=0; p<BM/32; ++p){
      int idx = p*256 + tid;
      int row = idx>>3, c8 = idx&7;
      int kq = c8>>1, pl = c8&1;
      const ushort_t* src = (pl? Alw : Ah) + (long)(bm0+row)*K + k0 + kq*8;
      uint4 v = *(const uint4*)src;
      *(uint4*)&Al[row][(c8 ^ (row&7))<<3] = v;
    }
    // stage B: 128 rows (clamped to N-1)
    #pragma unroll
    for (int p=0; p<4; ++p){
      int idx = p*256 + tid;
      int row = idx>>3, c8 = idx&7;
      int kq = c8>>1, pl = c8&1;
      int rn = bn0+row; if (rn > N-1) rn = N-1;
      const ushort_t* src = (pl? Blo : Bhi) + (long)rn*K + k0 + kq*8;
      uint4 v = *(const uint4*)src;
      *(uint4*)&Bl[row][(c8 ^ (row&7))<<3] = v;
    }
    __syncthreads();
    bf16x8 bh[4], bl[4];
    #pragma unroll
    for (int nt=0; nt<4; ++nt){
      int r = wn*64 + nt*16 + lr;
      bh[nt] = *(const bf16x8*)&Bl[r][((2*q)   ^ (r&7))<<3];
      bl[nt] = *(const bf16x8*)&Bl[r][((2*q+1) ^ (r&7))<<3];
    }
    #pragma unroll
    for (int mt=0; mt<MT; ++mt){
      int r = wm*(BM/2) + mt*16 + lr;
      bf16x8 ah = *(const bf16x8*)&Al[r][((2*q)   ^ (r&7))<<3];
      bf16x8 al = *(const bf16x8*)&Al[r][((2*q+1) ^ (r&7))<<3];
      #pragma unroll
      for (int nt=0; nt<4; ++nt){
        acc[mt][nt] = __builtin_amdgcn_mfma_f32_16x16x32_bf16(al, bh[nt], acc[mt][nt], 0,0,0);
        acc[mt][nt] = __builtin_amdgcn_mfma_f32_16x16x32_bf16(ah, bl[nt], acc[mt][nt], 0,0,0);
        acc[mt][nt] = __builtin_amdgcn_mfma_f32_16x16x32_bf16(ah, bh[nt], acc[mt][nt], 0,0,0);
      }
    }
    __syncthreads();
  }
  // epilogue: C/D frag: col = lane&15, row = (lane>>4)*4 + reg
  #pragma unroll
  for (int mt=0; mt<MT; ++mt){
    #pragma unroll
    for (int nt=0; nt<4; ++nt){
      #pragma unroll
      for (int r=0; r<4; ++r){
        int row = bm0 + wm*(BM/2) + mt*16 + q*4 + r;
        int col = bn0 + wn*64 + nt*16 + lr;
        if (col < N){
          float v = acc[mt][nt][r];
          if (EPI==1) v += bias[col];
          Cz[(long)row*ldc + col] = v;
          if (EPI==2){
            ushort_t h = f2bf(v);
            (Phi + (long)z*Czoff)[(long)row*ldp + col] = h;
            (Plo + (long)z*Czoff)[(long)row*ldp + col] = f2bf(v - bf2f(h));
          }
        }
      }
    }
  }
}

// ---------------- depthwise conv (both dirs) + bias + SiLU -> fp32 + bf16 planes ----
template<int KC>
__global__ __launch_bounds__(256) void conv_kernel(
  const float* __restrict__ xz, const float* __restrict__ w, const float* __restrict__ cb,
  float* __restrict__ xi, ushort_t* __restrict__ xih, ushort_t* __restrict__ xil)
{
  int idx = blockIdx.x*256 + threadIdx.x;   // R*DI threads
  int c = idx & (DI-1);
  int t = (idx >> 9) & (L_SEQ-1);
  int bb = idx >> 18;
  const float* base = xz + ((size_t)bb*L_SEQ)*1024 + c;
  float wr[KC];
  #pragma unroll
  for (int j=0;j<KC;j++) wr[j] = w[c*KC+j];
  float bias = cb[c];
  float accF = bias, accR = bias;
  #pragma unroll
  for (int j=0;j<KC;j++){
    int tf = t - (KC-1) + j;
    if (tf >= 0)     accF += wr[j]*base[(size_t)tf*1024];
    int tr = t + (KC-1) - j;
    if (tr < L_SEQ)  accR += wr[j]*base[(size_t)tr*1024];
  }
  const size_t RD = (size_t)R_ROWS*DI;
  float sF = siluf(accF), sR = siluf(accR);
  xi[idx] = sF; xi[RD+idx] = sR;
  ushort_t hF = f2bf(sF), hR = f2bf(sR);
  xih[idx] = hF;      xil[idx] = f2bf(sF - bf2f(hF));
  xih[RD+idx] = hR;   xil[RD+idx] = f2bf(sR - bf2f(hR));
}

// ---------------- selective scan, both dirs, dt-GEMM fused ----------------
__global__ __launch_bounds__(256) void scan_kernel(
  const float* __restrict__ xd,    // [2R,80]
  const float* __restrict__ xi,    // [2R,512]
  const float* __restrict__ xz,    // [R,1024] (z = cols 512..1023)
  const float* __restrict__ WdtW,  // [512,16]
  const float* __restrict__ dtb,   // [512]
  const float* __restrict__ Alog,  // [512,32]
  const float* __restrict__ Dp,    // [512]
  ushort_t* __restrict__ yh, ushort_t* __restrict__ yl, int col0)  // [2,R,1024]
{
  int bi = blockIdx.x;
  int dir = bi >> 9, b = (bi >> 6) & 7, d0 = (bi & 63) * 8;
  const float* xdp = xd + (size_t)dir*R_ROWS*80;
  const float* xip = xi + (size_t)dir*R_ROWS*DI;
  ushort_t* yoh = yh + (size_t)dir*R_ROWS*1024 + col0;
  ushort_t* yol = yl + (size_t)dir*R_ROWS*1024 + col0;
  size_t bL = (size_t)b*L_SEQ;

  __shared__ float  XD[32][84];
  __shared__ float  HC[8][16][36];
  __shared__ float2 DTs[32][8];
  __shared__ float2 XZs[32][8];
  __shared__ float  YO[32][8];
  __shared__ float  WT[16][8];
  __shared__ float  DTB[8], DPS[8];

  int tid = threadIdx.x;
  if (tid < 128){ int k = tid>>3, cc = tid&7; WT[k][cc] = WdtW[(d0+cc)*DTR + k]; }
  else if (tid < 136) DTB[tid-128] = dtb[d0 + tid-128];
  else if (tid < 144) DPS[tid-136] = Dp[d0 + tid-136];

  int wv = tid>>6, l64 = tid&63;
  int ch = wv*2 + (l64>>5);
  int n  = l64 & 31;
  float Al = -__expf(Alog[(d0+ch)*NSTATE + n]) * 1.44269504089f;
  float h = 0.f;

  int li8 = tid>>3, c8 = tid&7;
  int chD = tid>>5, t2 = tid&31;

  for (int chunk=0; chunk<16; ++chunk){
    int s0 = chunk*32;
    if (chunk){
      int st = s0 - 32 + li8;
      int t = dir ? (L_SEQ-1-st) : st;
      float v = YO[li8][c8];
      ushort_t hh = f2bf(v);
      yoh[(bL + t)*1024 + d0 + c8] = hh;
      yol[(bL + t)*1024 + d0 + c8] = f2bf(v - bf2f(hh));
    }
    {
      int rr = tid>>3, ee = tid&7;
      int st = s0 + rr; int t = dir ? (L_SEQ-1-st) : st;
      const float* src = xdp + (bL + t)*80;
      #pragma unroll
      for (int j=0;j<10;j++) XD[rr][ee + j*8] = src[ee + j*8];
      XZs[li8][c8] = make_float2(xip[(bL + t)*DI + d0 + c8],
                                 xz[(bL + t)*1024 + DI + d0 + c8]);
    }
    __syncthreads();
    {
      float s = DTB[c8];
      #pragma unroll
      for (int k=0;k<DTR;k++) s = fmaf(XD[li8][k], WT[k][c8], s);
      float dtv = fmaxf(s,0.f) + log1pf(__expf(-fabsf(s)));
      DTs[li8][c8] = make_float2(dtv, dtv * XZs[li8][c8].x);
    }
    __syncthreads();
    #pragma unroll
    for (int half=0; half<2; ++half){
      #pragma unroll
      for (int li=0; li<16; ++li){
        int li2 = half*16 + li;
        float2 dd = DTs[li2][ch];
        float Bv = XD[li2][DTR + n];
        float Cv = XD[li2][DTR + NSTATE + n];
        float dA = __builtin_amdgcn_exp2f(dd.x * Al);
        h = fmaf(dA, h, dd.y * Bv);
        HC[ch][li][n] = h * Cv;
      }
      __syncthreads();
      {
        int t = t2 >> 1, nh = t2 & 1;
        const float* hp = &HC[chD][t][nh*16];
        float4 s1 = *(const float4*)&hp[0];
        float4 s2 = *(const float4*)&hp[4];
        float4 s3 = *(const float4*)&hp[8];
        float4 s4 = *(const float4*)&hp[12];
        float ssum = ((s1.x+s1.y)+(s1.z+s1.w)) + ((s2.x+s2.y)+(s2.z+s2.w))
                   + ((s3.x+s3.y)+(s3.z+s3.w)) + ((s4.x+s4.y)+(s4.z+s4.w));
        ssum += __shfl_xor(ssum, 1);
        if (!nh){
          int li2 = half*16 + t;
          float2 xzv = XZs[li2][chD];
          YO[li2][chD] = (ssum + xzv.x * DPS[chD]) * siluf(xzv.y);
        }
      }
      __syncthreads();
    }
  }
  {
    int st = 480 + li8;
    int t = dir ? (L_SEQ-1-st) : st;
    float v = YO[li8][c8];
    ushort_t hh = f2bf(v);
    yoh[(bL + t)*1024 + d0 + c8] = hh;
    yol[(bL + t)*1024 + d0 + c8] = f2bf(v - bf2f(hh));
  }
}

// ---------------- gate + fuse -> bf16 planes of fused ----------------
__global__ __launch_bounds__(256) void fuse_kernel(const float* __restrict__ gpre,
   const float* __restrict__ gb, const float* __restrict__ ffr,
   ushort_t* __restrict__ fush, ushort_t* __restrict__ fusl)
{
  int idx = blockIdx.x*256 + threadIdx.x;
  int r = idx >> 8, c = idx & (DM-1);
  size_t ro = (size_t)r*2*DM;
  float ffv = ffr[ro + c];
  float frv = ffr[ro + DM + c];
  float g = 1.f/(1.f+__expf(-(gpre[idx] + gb[c])));
  float v = g*ffv + (1.f-g)*frv;
  ushort_t h = f2bf(v);
  fush[idx] = h;
  fusl[idx] = f2bf(v - bf2f(h));
}

extern "C" void kernel_launch(void* const* d_in, const int* in_sizes, int n_in,
                              void* d_out, int out_size, void* d_ws, size_t ws_size,
                              hipStream_t stream)
{
  (void)in_sizes; (void)n_in; (void)out_size; (void)ws_size;
  const float* x    = (const float*)d_in[0];
  const float* ln_g = (const float*)d_in[1];
  const float* ln_b = (const float*)d_in[2];
  const float* Win[2]  = {(const float*)d_in[3],  (const float*)d_in[12]};
  const float* convw[2]= {(const float*)d_in[4],  (const float*)d_in[13]};
  const float* convb[2]= {(const float*)d_in[5],  (const float*)d_in[14]};
  const float* Wx[2]   = {(const float*)d_in[6],  (const float*)d_in[15]};
  const float* Wdt[2]  = {(const float*)d_in[7],  (const float*)d_in[16]};
  const float* dtb[2]  = {(const float*)d_in[8],  (const float*)d_in[17]};
  const float* Alog[2] = {(const float*)d_in[9],  (const float*)d_in[18]};
  const float* Dpp[2]  = {(const float*)d_in[10], (const float*)d_in[19]};
  const float* Wout[2] = {(const float*)d_in[11], (const float*)d_in[20]};
  const float* gate_W = (const float*)d_in[21];
  const float* gate_b = (const float*)d_in[22];
  const float* op_W   = (const float*)d_in[23];
  const float* op_b   = (const float*)d_in[24];
  float* out = (float*)d_out;

  char* wsb = (char*)d_ws;
  size_t off = 0;
  auto allocB = [&](size_t bytes)->char*{
    char* p = wsb + off; off += (bytes + 15) & ~size_t(15); return p; };
  const size_t R = R_ROWS;

  // fp32 buffers
  float* xzb  = (float*)allocB(R*1024*4);
  float* xi   = (float*)allocB(2*R*DI*4);
  float* xdd  = (float*)allocB(2*R*80*4);
  float* ffr  = (float*)allocB(R*2*DM*4);
  float* gpre = (float*)allocB(R*DM*4);
  // bf16 plane buffers
  ushort_t* xnh = (ushort_t*)allocB(R*DM*2);
  ushort_t* xnl = (ushort_t*)allocB(R*DM*2);
  ushort_t* xih = (ushort_t*)allocB(2*R*DI*2);
  ushort_t* xil = (ushort_t*)allocB(2*R*DI*2);
  ushort_t* yhp = (ushort_t*)allocB(2*R*1024*2);
  ushort_t* ylp = (ushort_t*)allocB(2*R*1024*2);
  ushort_t* ffh = (ushort_t*)allocB(R*2*DM*2);
  ushort_t* ffl = (ushort_t*)allocB(R*2*DM*2);
  ushort_t* fsh = (ushort_t*)allocB(R*DM*2);
  ushort_t* fsl = (ushort_t*)allocB(R*DM*2);
  // weight planes
  ushort_t* WiH[2] = {(ushort_t*)allocB(262144*2), (ushort_t*)allocB(262144*2)};
  ushort_t* WiL[2] = {(ushort_t*)allocB(262144*2), (ushort_t*)allocB(262144*2)};
  ushort_t* WxH[2] = {(ushort_t*)allocB(40960*2),  (ushort_t*)allocB(40960*2)};
  ushort_t* WxL[2] = {(ushort_t*)allocB(40960*2),  (ushort_t*)allocB(40960*2)};
  ushort_t* WoH = (ushort_t*)allocB(262144*2);
  ushort_t* WoL = (ushort_t*)allocB(262144*2);
  ushort_t* gH  = (ushort_t*)allocB(131072*2);
  ushort_t* gL  = (ushort_t*)allocB(131072*2);
  ushort_t* oH  = (ushort_t*)allocB(65536*2);
  ushort_t* oL  = (ushort_t*)allocB(65536*2);

  prep_weights<<<4160, 256, 0, stream>>>(Win[0], Win[1], Wx[0], Wx[1],
      Wout[0], Wout[1], gate_W, op_W,
      WiH[0], WiL[0], WiH[1], WiL[1], WxH[0], WxL[0], WxH[1], WxL[1],
      WoH, WoL, gH, gL, oH, oL);

  ln_kernel<<<R/4, 256, 0, stream>>>(x, ln_g, ln_b, xnh, xnl);

  for (int m=0; m<2; ++m){
    // xz = xn @ Win^T   [4096,256] x [1024,256]^T
    gemm_mfma<128,0><<<dim3(8, 32, 1), 256, 0, stream>>>(
        xnh, xnl, 0, WiH[m], WiL[m], DM, 1024, xzb, 1024, 0,
        nullptr, nullptr, 0, nullptr);
    if (m==0) conv_kernel<4><<<8192,256,0,stream>>>(xzb, convw[m], convb[m], xi, xih, xil);
    else      conv_kernel<8><<<8192,256,0,stream>>>(xzb, convw[m], convb[m], xi, xih, xil);
    // x_dbl = xi @ Wx^T  [8192,512] x [80,512]^T
    gemm_mfma<64,0><<<dim3(1, 128, 1), 256, 0, stream>>>(
        xih, xil, 0, WxH[m], WxL[m], DI, 80, xdd, 80, 0,
        nullptr, nullptr, 0, nullptr);
    // scan (dt fused), both dirs -> y bf16 planes at col m*512
    scan_kernel<<<1024, 256, 0, stream>>>(xdd, xi, xzb, Wdt[m], dtb[m], Alog[m], Dpp[m],
                                          yhp, ylp, m*512);
  }
  // f_dir = y[dir] @ [Wout0;Wout1]^T  (K=1024), z=dir -> ffr cols dir*256..
  gemm_mfma<128,2><<<dim3(2, 32, 2), 256, 0, stream>>>(
      yhp, ylp, (long)R*1024, WoH, WoL, 1024, 256, ffr, 2*DM, DM,
      ffh, ffl, 2*DM, nullptr);
  // gate pre-activation: ffr @ gate_W^T  [4096,512] x [256,512]^T
  gemm_mfma<64,0><<<dim3(2, 64, 1), 256, 0, stream>>>(
      ffh, ffl, 0, gH, gL, 2*DM, DM, gpre, DM, 0,
      nullptr, nullptr, 0, nullptr);
  fuse_kernel<<<R*DM/256, 256, 0, stream>>>(gpre, gate_b, ffr, fsh, fsl);
  // out = fused @ op_W^T + op_b
  gemm_mfma<64,1><<<dim3(2, 64, 1), 256, 0, stream>>>(
      fsh, fsl, 0, oH, oL, DM, DM, out, DM, 0,
      nullptr, nullptr, 0, op_b);
}